// Round 1
// baseline (339.093 us; speedup 1.0000x reference)
//
#include <hip/hip_runtime.h>

// MHA forward: qkv GEMM (bf16x3 split MFMA) -> flash attention -> proj GEMM.
// B=2, N=2048, C=1024, H=16, D=64. SCALE=0.125 folded into Q at QKV epilogue.

typedef unsigned short u16;
typedef __attribute__((ext_vector_type(8))) short bf16x8;
typedef __attribute__((ext_vector_type(4))) float f32x4;

#define DEV static __device__ __forceinline__
#define MFMA(a, b, c) __builtin_amdgcn_mfma_f32_16x16x32_bf16(a, b, c, 0, 0, 0)

DEV u16 f2bf(float f) {
  unsigned u = __float_as_uint(f);
  return (u16)((u + 0x7fffu + ((u >> 16) & 1u)) >> 16);  // RNE
}
DEV float bf2f(u16 h) { return __uint_as_float(((unsigned)h) << 16); }

DEV void async16(u16* dst, const u16* src) {
  __builtin_amdgcn_global_load_lds(
      (const __attribute__((address_space(1))) unsigned int*)(const void*)src,
      (__attribute__((address_space(3))) unsigned int*)(void*)dst, 16, 0, 0);
}

// ---------------- split fp32 -> bf16 hi/lo ----------------
__global__ __launch_bounds__(256) void k_split(const float* __restrict__ src,
                                               u16* __restrict__ dh,
                                               u16* __restrict__ dl, int n4) {
  int i = blockIdx.x * 256 + threadIdx.x;
  if (i >= n4) return;
  float4 v = ((const float4*)src)[i];
  ushort4 h, l;
  h.x = f2bf(v.x); l.x = f2bf(v.x - bf2f(h.x));
  h.y = f2bf(v.y); l.y = f2bf(v.y - bf2f(h.y));
  h.z = f2bf(v.z); l.z = f2bf(v.z - bf2f(h.z));
  h.w = f2bf(v.w); l.w = f2bf(v.w - bf2f(h.w));
  ((ushort4*)dh)[i] = h;
  ((ushort4*)dl)[i] = l;
}

// ---------------- GEMM: C[M][N] = A[M][1024] . B[N][1024]^T + bias ----------------
// 128x128 tile, BK=64, 4 waves (2x2), bf16x3 split (hh + hl + lh).
// MODE 0: epilogue routes QKV -> split Q (scaled), K, V-transposed tensors.
// MODE 1: plain fp32 store to fout.
template <int MODE>
__global__ __launch_bounds__(256) void k_gemm(
    const u16* __restrict__ Ah_g, const u16* __restrict__ Al_g,
    const u16* __restrict__ Bh_g, const u16* __restrict__ Bl_g,
    const float* __restrict__ bias,
    u16* __restrict__ oQh, u16* __restrict__ oQl,
    u16* __restrict__ oKh, u16* __restrict__ oKl,
    u16* __restrict__ oVh, u16* __restrict__ oVl,
    float* __restrict__ fout, int nbn) {
  // LDS: Ah[128][64] @0, Al @8192, Bh @16384, Bl @24576 (u16 units), 64KB.
  __shared__ u16 lds[32768];
  const int t = threadIdx.x;
  const int lane = t & 63, g = lane >> 4, cl = lane & 15;
  const int w = t >> 6;
  const int mi = blockIdx.x / nbn, ni = blockIdx.x % nbn;
  const int m0 = mi * 128, n0 = ni * 128;
  const int wr = (w >> 1) * 64, wc = (w & 1) * 64;

  f32x4 acc[4][4] = {};

  for (int kt = 0; kt < 16; ++kt) {
    const int k0 = kt * 64;
    // stage 4 tensors x 1024 slots of 16B, linear LDS dest, swizzled source
#pragma unroll
    for (int j = 0; j < 16; ++j) {
      int gs = j * 256 + t;
      int tensor = gs >> 10;
      int s = gs & 1023;
      int row = s >> 3;
      int c = (s & 7) ^ (row & 7);
      const u16* src;
      if (tensor == 0)      src = Ah_g + (m0 + row) * 1024 + k0 + c * 8;
      else if (tensor == 1) src = Al_g + (m0 + row) * 1024 + k0 + c * 8;
      else if (tensor == 2) src = Bh_g + (n0 + row) * 1024 + k0 + c * 8;
      else                  src = Bl_g + (n0 + row) * 1024 + k0 + c * 8;
      async16(&lds[(unsigned)(gs & ~63) * 8], src);
    }
    __syncthreads();

#pragma unroll
    for (int ks = 0; ks < 2; ++ks) {
      bf16x8 af[4][2], bfr[4][2];
#pragma unroll
      for (int fm = 0; fm < 4; ++fm) {
        int rowL = wr + fm * 16 + cl;
        int idx = rowL * 64 + (((4 * ks + g) ^ (rowL & 7)) * 8);
        af[fm][0] = *(const bf16x8*)&lds[idx];
        af[fm][1] = *(const bf16x8*)&lds[8192 + idx];
      }
#pragma unroll
      for (int fn = 0; fn < 4; ++fn) {
        int rowL = wc + fn * 16 + cl;
        int idx = rowL * 64 + (((4 * ks + g) ^ (rowL & 7)) * 8);
        bfr[fn][0] = *(const bf16x8*)&lds[16384 + idx];
        bfr[fn][1] = *(const bf16x8*)&lds[24576 + idx];
      }
#pragma unroll
      for (int fm = 0; fm < 4; ++fm)
#pragma unroll
        for (int fn = 0; fn < 4; ++fn) {
          acc[fm][fn] = MFMA(af[fm][0], bfr[fn][0], acc[fm][fn]);
          acc[fm][fn] = MFMA(af[fm][0], bfr[fn][1], acc[fm][fn]);
          acc[fm][fn] = MFMA(af[fm][1], bfr[fn][0], acc[fm][fn]);
        }
    }
    __syncthreads();
  }

  // epilogue
#pragma unroll
  for (int fm = 0; fm < 4; ++fm) {
#pragma unroll
    for (int fn = 0; fn < 4; ++fn) {
      int cc = n0 + wc + fn * 16 + cl;
      float bv = bias[cc];
      f32x4 a = acc[fm][fn];
#pragma unroll
      for (int r = 0; r < 4; ++r) {
        int rr = m0 + wr + fm * 16 + g * 4 + r;
        float v = a[r] + bv;
        if (MODE == 0) {
          int seg = cc >> 10, cm = cc & 1023;
          int h = cm >> 6, d = cm & 63;
          int b = rr >> 11, n = rr & 2047;
          int bh = b * 16 + h;
          if (seg == 0) {
            v *= 0.125f;  // SCALE folded into Q
            u16 hh = f2bf(v), ll = f2bf(v - bf2f(hh));
            int o = (bh * 2048 + n) * 64 + d;
            oQh[o] = hh; oQl[o] = ll;
          } else if (seg == 1) {
            u16 hh = f2bf(v), ll = f2bf(v - bf2f(hh));
            int o = (bh * 2048 + n) * 64 + d;
            oKh[o] = hh; oKl[o] = ll;
          } else {
            u16 hh = f2bf(v), ll = f2bf(v - bf2f(hh));
            int o = (bh * 64 + d) * 2048 + n;  // V stored transposed [bh][d][n]
            oVh[o] = hh; oVl[o] = ll;
          }
        } else {
          fout[rr * 1024 + cc] = v;
        }
      }
    }
  }
}

// ---------------- flash attention ----------------
// grid 512 (bh-major with XCD chunk swizzle), 4 waves x 32 q-rows = 128 q-rows/block.
// KV tile = 64 keys. Online softmax; P split hi/lo via per-wave LDS; 3-term MFMA.
__global__ __launch_bounds__(256) void k_attn(
    const u16* __restrict__ Qh, const u16* __restrict__ Ql,
    const u16* __restrict__ Kh, const u16* __restrict__ Kl,
    const u16* __restrict__ Vh, const u16* __restrict__ Vl,
    u16* __restrict__ Oh, u16* __restrict__ Ol) {
  // LDS u16 units: K_h @0 [64][64], K_l @4096, Vt_h @8192 [64 d][64 n], Vt_l @12288,
  // P per wave: Ph @16384+w*4096, Pl = Ph+2048. Total 64KB.
  __shared__ u16 lds[32768];
  const int t = threadIdx.x, w = t >> 6, lane = t & 63, g = lane >> 4, cl = lane & 15;
  int bid = (blockIdx.x & 7) * 64 + (blockIdx.x >> 3);  // same-bh blocks -> same XCD
  const int bh = bid >> 4, qt = bid & 15;
  const int n0 = qt * 128;
  const int PH = 16384 + w * 4096;

  // Q fragments in registers (pre-scaled by SCALE at QKV epilogue)
  bf16x8 qfh[2][2], qfl[2][2];
#pragma unroll
  for (int fm = 0; fm < 2; ++fm) {
    int rg = bh * 2048 + n0 + w * 32 + fm * 16 + cl;
#pragma unroll
    for (int ks = 0; ks < 2; ++ks) {
      qfh[fm][ks] = *(const bf16x8*)&Qh[rg * 64 + ks * 32 + g * 8];
      qfl[fm][ks] = *(const bf16x8*)&Ql[rg * 64 + ks * 32 + g * 8];
    }
  }

  f32x4 o[2][4] = {};
  float mrow[2][4], lrow[2][4];
#pragma unroll
  for (int fm = 0; fm < 2; ++fm)
#pragma unroll
    for (int r = 0; r < 4; ++r) { mrow[fm][r] = -1e30f; lrow[fm][r] = 0.f; }

  for (int kt = 0; kt < 32; ++kt) {
    // stage K tile [key][d] and Vt tile [d][key], swizzled source, linear dest
#pragma unroll
    for (int j = 0; j < 8; ++j) {
      int gs = j * 256 + t;
      int tensor = gs >> 9, s = gs & 511, row = s >> 3;
      int c = (s & 7) ^ (row & 7);
      const u16* src;
      if (tensor == 0)      src = Kh + (bh * 2048 + kt * 64 + row) * 64 + c * 8;
      else if (tensor == 1) src = Kl + (bh * 2048 + kt * 64 + row) * 64 + c * 8;
      else if (tensor == 2) src = Vh + (bh * 64 + row) * 2048 + kt * 64 + c * 8;
      else                  src = Vl + (bh * 64 + row) * 2048 + kt * 64 + c * 8;
      async16(&lds[(unsigned)(gs & ~63) * 8], src);
    }
    __syncthreads();

    // S = Q.K^T (3-term split)
    f32x4 sc_[2][4] = {};
#pragma unroll
    for (int fn = 0; fn < 4; ++fn) {
      int krow = fn * 16 + cl;
#pragma unroll
      for (int ks = 0; ks < 2; ++ks) {
        int idx = krow * 64 + (((4 * ks + g) ^ (krow & 7)) * 8);
        bf16x8 kfh = *(const bf16x8*)&lds[idx];
        bf16x8 kfl = *(const bf16x8*)&lds[4096 + idx];
#pragma unroll
        for (int fm = 0; fm < 2; ++fm) {
          sc_[fm][fn] = MFMA(qfh[fm][ks], kfh, sc_[fm][fn]);
          sc_[fm][fn] = MFMA(qfh[fm][ks], kfl, sc_[fm][fn]);
          sc_[fm][fn] = MFMA(qfl[fm][ks], kfh, sc_[fm][fn]);
        }
      }
    }

    // online softmax + P split write
#pragma unroll
    for (int fm = 0; fm < 2; ++fm) {
      float rmax[4], mnew[4], esc[4], rsum[4];
#pragma unroll
      for (int r = 0; r < 4; ++r)
        rmax[r] = fmaxf(fmaxf(sc_[fm][0][r], sc_[fm][1][r]),
                        fmaxf(sc_[fm][2][r], sc_[fm][3][r]));
#pragma unroll
      for (int r = 0; r < 4; ++r) {
#pragma unroll
        for (int off = 1; off < 16; off <<= 1)
          rmax[r] = fmaxf(rmax[r], __shfl_xor(rmax[r], off));
      }
#pragma unroll
      for (int r = 0; r < 4; ++r) {
        mnew[r] = fmaxf(mrow[fm][r], rmax[r]);
        esc[r] = __expf(mrow[fm][r] - mnew[r]);
        mrow[fm][r] = mnew[r];
        rsum[r] = 0.f;
      }
#pragma unroll
      for (int fn = 0; fn < 4; ++fn)
#pragma unroll
        for (int r = 0; r < 4; ++r) {
          float p = __expf(sc_[fm][fn][r] - mnew[r]);
          sc_[fm][fn][r] = p;
          rsum[r] += p;
        }
#pragma unroll
      for (int r = 0; r < 4; ++r) {
#pragma unroll
        for (int off = 1; off < 16; off <<= 1) rsum[r] += __shfl_xor(rsum[r], off);
        lrow[fm][r] = lrow[fm][r] * esc[r] + rsum[r];
      }
#pragma unroll
      for (int fd = 0; fd < 4; ++fd)
#pragma unroll
        for (int r = 0; r < 4; ++r) o[fm][fd][r] *= esc[r];
#pragma unroll
      for (int fn = 0; fn < 4; ++fn)
#pragma unroll
        for (int r = 0; r < 4; ++r) {
          float p = sc_[fm][fn][r];
          u16 ph = f2bf(p);
          u16 pl = f2bf(p - bf2f(ph));
          int prow = fm * 16 + g * 4 + r;
          int idx = (prow * 64 + fn * 16 + cl) ^ ((prow & 7) << 3);
          lds[PH + idx] = ph;
          lds[PH + 2048 + idx] = pl;
        }
    }

    // O += P.V (3-term split)
    bf16x8 pfh[2][2], pfl[2][2];
#pragma unroll
    for (int fm = 0; fm < 2; ++fm) {
      int prow = fm * 16 + cl;
#pragma unroll
      for (int ks = 0; ks < 2; ++ks) {
        int idx = (prow * 64 + (4 * ks + g) * 8) ^ ((prow & 7) << 3);
        pfh[fm][ks] = *(const bf16x8*)&lds[PH + idx];
        pfl[fm][ks] = *(const bf16x8*)&lds[PH + 2048 + idx];
      }
    }
#pragma unroll
    for (int fd = 0; fd < 4; ++fd) {
      int vrow = fd * 16 + cl;
#pragma unroll
      for (int ks = 0; ks < 2; ++ks) {
        int idx = vrow * 64 + (((4 * ks + g) ^ (vrow & 7)) * 8);
        bf16x8 vfh = *(const bf16x8*)&lds[8192 + idx];
        bf16x8 vfl = *(const bf16x8*)&lds[12288 + idx];
#pragma unroll
        for (int fm = 0; fm < 2; ++fm) {
          o[fm][fd] = MFMA(pfh[fm][ks], vfh, o[fm][fd]);
          o[fm][fd] = MFMA(pfh[fm][ks], vfl, o[fm][fd]);
          o[fm][fd] = MFMA(pfl[fm][ks], vfh, o[fm][fd]);
        }
      }
    }
    __syncthreads();
  }

  // normalize + write O (split, [token][h*64+d] layout for proj GEMM)
  const int b = bh >> 4, h = bh & 15;
#pragma unroll
  for (int fm = 0; fm < 2; ++fm) {
    float inv[4];
#pragma unroll
    for (int r = 0; r < 4; ++r) inv[r] = 1.0f / lrow[fm][r];
#pragma unroll
    for (int fd = 0; fd < 4; ++fd)
#pragma unroll
      for (int r = 0; r < 4; ++r) {
        float v = o[fm][fd][r] * inv[r];
        u16 hh = f2bf(v), ll = f2bf(v - bf2f(hh));
        int rowg = b * 2048 + n0 + w * 32 + fm * 16 + g * 4 + r;
        int colg = h * 64 + fd * 16 + cl;
        Oh[rowg * 1024 + colg] = hh;
        Ol[rowg * 1024 + colg] = ll;
      }
  }
}

extern "C" void kernel_launch(void* const* d_in, const int* in_sizes, int n_in,
                              void* d_out, int out_size, void* d_ws, size_t ws_size,
                              hipStream_t stream) {
  const float* x  = (const float*)d_in[0];
  const float* Wq = (const float*)d_in[1];
  const float* bq = (const float*)d_in[2];
  const float* Wp = (const float*)d_in[3];
  const float* bp = (const float*)d_in[4];
  float* out = (float*)d_out;
  char* ws = (char*)d_ws;

  // workspace layout (bytes); O aliases X (X dead after QKV GEMM)
  u16* Xh  = (u16*)(ws + 0);         // 8388608  (also Oh)
  u16* Xl  = (u16*)(ws + 8388608);   // 8388608  (also Ol)
  u16* Wqh = (u16*)(ws + 16777216);  // 6291456
  u16* Wql = (u16*)(ws + 23068672);  // 6291456
  u16* Wph = (u16*)(ws + 29360128);  // 2097152
  u16* Wpl = (u16*)(ws + 31457280);  // 2097152
  u16* Qh  = (u16*)(ws + 33554432);  // 8388608
  u16* Ql  = (u16*)(ws + 41943040);
  u16* Kh  = (u16*)(ws + 50331648);
  u16* Kl  = (u16*)(ws + 58720256);
  u16* Vh  = (u16*)(ws + 67108864);
  u16* Vl  = (u16*)(ws + 75497472);  // end 83886080 (80MB)

  k_split<<<1048576 / 256, 256, 0, stream>>>(x, Xh, Xl, 1048576);
  k_split<<<786432 / 256, 256, 0, stream>>>(Wq, Wqh, Wql, 786432);
  k_split<<<262144 / 256, 256, 0, stream>>>(Wp, Wph, Wpl, 262144);

  k_gemm<0><<<32 * 24, 256, 0, stream>>>(Xh, Xl, Wqh, Wql, bq,
                                         Qh, Ql, Kh, Kl, Vh, Vl, nullptr, 24);
  k_attn<<<512, 256, 0, stream>>>(Qh, Ql, Kh, Kl, Vh, Vl, Xh, Xl);
  k_gemm<1><<<32 * 8, 256, 0, stream>>>(Xh, Xl, Wph, Wpl, bp,
                                        nullptr, nullptr, nullptr, nullptr,
                                        nullptr, nullptr, out, 8);
}

// Round 2
// 276.132 us; speedup vs baseline: 1.2280x; 1.2280x over previous
//
#include <hip/hip_runtime.h>

// MHA forward: qkv GEMM (bf16x3 split MFMA) -> flash attention -> proj GEMM.
// B=2, N=2048, C=1024, H=16, D=64. SCALE=0.125 folded into Q at QKV epilogue.
// R2: attn rewritten with swapped QK^T (lane-owns-row softmax), 2-term PV,
//     b64 P writes to per-wave LDS (no barrier), setprio around MFMA.

typedef unsigned short u16;
typedef __attribute__((ext_vector_type(8))) short bf16x8;
typedef __attribute__((ext_vector_type(4))) float f32x4;

#define DEV static __device__ __forceinline__
#define MFMA(a, b, c) __builtin_amdgcn_mfma_f32_16x16x32_bf16(a, b, c, 0, 0, 0)

DEV u16 f2bf(float f) {
  unsigned u = __float_as_uint(f);
  return (u16)((u + 0x7fffu + ((u >> 16) & 1u)) >> 16);  // RNE
}
DEV float bf2f(u16 h) { return __uint_as_float(((unsigned)h) << 16); }

DEV void async16(u16* dst, const u16* src) {
  __builtin_amdgcn_global_load_lds(
      (const __attribute__((address_space(1))) unsigned int*)(const void*)src,
      (__attribute__((address_space(3))) unsigned int*)(void*)dst, 16, 0, 0);
}

// ---------------- split fp32 -> bf16 hi/lo (all three inputs, one launch) ----
__global__ __launch_bounds__(256) void k_split_all(
    const float* __restrict__ x, const float* __restrict__ wq,
    const float* __restrict__ wp, u16* __restrict__ xh, u16* __restrict__ xl,
    u16* __restrict__ wqh, u16* __restrict__ wql, u16* __restrict__ wph,
    u16* __restrict__ wpl) {
  int i = blockIdx.x * 256 + threadIdx.x;
  const float* src;
  u16 *dh, *dl;
  int off;
  if (i < 1048576) { src = x;  dh = xh;  dl = xl;  off = i; }
  else if (i < 1835008) { src = wq; dh = wqh; dl = wql; off = i - 1048576; }
  else { src = wp; dh = wph; dl = wpl; off = i - 1835008; }
  float4 v = ((const float4*)src)[off];
  ushort4 h, l;
  h.x = f2bf(v.x); l.x = f2bf(v.x - bf2f(h.x));
  h.y = f2bf(v.y); l.y = f2bf(v.y - bf2f(h.y));
  h.z = f2bf(v.z); l.z = f2bf(v.z - bf2f(h.z));
  h.w = f2bf(v.w); l.w = f2bf(v.w - bf2f(h.w));
  ((ushort4*)dh)[off] = h;
  ((ushort4*)dl)[off] = l;
}

// ---------------- GEMM: C[M][N] = A[M][1024] . B[N][1024]^T + bias ----------------
// 128x128 tile, BK=64, 4 waves (2x2), bf16x3 split (hh + hl + lh).
template <int MODE>
__global__ __launch_bounds__(256) void k_gemm(
    const u16* __restrict__ Ah_g, const u16* __restrict__ Al_g,
    const u16* __restrict__ Bh_g, const u16* __restrict__ Bl_g,
    const float* __restrict__ bias,
    u16* __restrict__ oQh, u16* __restrict__ oQl,
    u16* __restrict__ oKh, u16* __restrict__ oKl,
    u16* __restrict__ oVh, u16* __restrict__ oVl,
    float* __restrict__ fout, int nbn) {
  __shared__ u16 lds[32768];
  const int t = threadIdx.x;
  const int lane = t & 63, g = lane >> 4, cl = lane & 15;
  const int w = t >> 6;
  const int mi = blockIdx.x / nbn, ni = blockIdx.x % nbn;
  const int m0 = mi * 128, n0 = ni * 128;
  const int wr = (w >> 1) * 64, wc = (w & 1) * 64;

  f32x4 acc[4][4] = {};

  for (int kt = 0; kt < 16; ++kt) {
    const int k0 = kt * 64;
#pragma unroll
    for (int j = 0; j < 16; ++j) {
      int gs = j * 256 + t;
      int tensor = gs >> 10;
      int s = gs & 1023;
      int row = s >> 3;
      int c = (s & 7) ^ (row & 7);
      const u16* src;
      if (tensor == 0)      src = Ah_g + (m0 + row) * 1024 + k0 + c * 8;
      else if (tensor == 1) src = Al_g + (m0 + row) * 1024 + k0 + c * 8;
      else if (tensor == 2) src = Bh_g + (n0 + row) * 1024 + k0 + c * 8;
      else                  src = Bl_g + (n0 + row) * 1024 + k0 + c * 8;
      async16(&lds[(unsigned)(gs & ~63) * 8], src);
    }
    __syncthreads();

#pragma unroll
    for (int ks = 0; ks < 2; ++ks) {
      bf16x8 af[4][2], bfr[4][2];
#pragma unroll
      for (int fm = 0; fm < 4; ++fm) {
        int rowL = wr + fm * 16 + cl;
        int idx = rowL * 64 + (((4 * ks + g) ^ (rowL & 7)) * 8);
        af[fm][0] = *(const bf16x8*)&lds[idx];
        af[fm][1] = *(const bf16x8*)&lds[8192 + idx];
      }
#pragma unroll
      for (int fn = 0; fn < 4; ++fn) {
        int rowL = wc + fn * 16 + cl;
        int idx = rowL * 64 + (((4 * ks + g) ^ (rowL & 7)) * 8);
        bfr[fn][0] = *(const bf16x8*)&lds[16384 + idx];
        bfr[fn][1] = *(const bf16x8*)&lds[24576 + idx];
      }
#pragma unroll
      for (int fm = 0; fm < 4; ++fm)
#pragma unroll
        for (int fn = 0; fn < 4; ++fn) {
          acc[fm][fn] = MFMA(af[fm][0], bfr[fn][0], acc[fm][fn]);
          acc[fm][fn] = MFMA(af[fm][0], bfr[fn][1], acc[fm][fn]);
          acc[fm][fn] = MFMA(af[fm][1], bfr[fn][0], acc[fm][fn]);
        }
    }
    __syncthreads();
  }

#pragma unroll
  for (int fm = 0; fm < 4; ++fm) {
#pragma unroll
    for (int fn = 0; fn < 4; ++fn) {
      int cc = n0 + wc + fn * 16 + cl;
      float bv = bias[cc];
      f32x4 a = acc[fm][fn];
#pragma unroll
      for (int r = 0; r < 4; ++r) {
        int rr = m0 + wr + fm * 16 + g * 4 + r;
        float v = a[r] + bv;
        if (MODE == 0) {
          int seg = cc >> 10, cm = cc & 1023;
          int h = cm >> 6, d = cm & 63;
          int b = rr >> 11, n = rr & 2047;
          int bh = b * 16 + h;
          if (seg == 0) {
            v *= 0.125f;
            u16 hh = f2bf(v), ll = f2bf(v - bf2f(hh));
            int o = (bh * 2048 + n) * 64 + d;
            oQh[o] = hh; oQl[o] = ll;
          } else if (seg == 1) {
            u16 hh = f2bf(v), ll = f2bf(v - bf2f(hh));
            int o = (bh * 2048 + n) * 64 + d;
            oKh[o] = hh; oKl[o] = ll;
          } else {
            u16 hh = f2bf(v), ll = f2bf(v - bf2f(hh));
            int o = (bh * 64 + d) * 2048 + n;  // V stored transposed [bh][d][n]
            oVh[o] = hh; oVl[o] = ll;
          }
        } else {
          fout[rr * 1024 + cc] = v;
        }
      }
    }
  }
}

// ---------------- flash attention (swapped QK^T) ----------------
// grid 512, 4 waves x 32 q-rows = 128 q-rows/block. KV tile = 64 keys.
// S^T = mfma(K,Q): lane (g,cl) holds S[q=base+cl][k=fn*16+4g+r]. Softmax is
// lane-local + 2 shuffles. P packed to bf16 pairs, b64-written to a private
// per-wave LDS region (XOR-swizzled, no barrier), read back as MFMA A-frags.
// PV is 2-term (ph*vh + ph*vl).
__global__ __launch_bounds__(256) void k_attn(
    const u16* __restrict__ Qh, const u16* __restrict__ Ql,
    const u16* __restrict__ Kh, const u16* __restrict__ Kl,
    const u16* __restrict__ Vh, const u16* __restrict__ Vl,
    u16* __restrict__ Oh, u16* __restrict__ Ol) {
  // LDS u16 units: K_h @0 [64][64], K_l @4096, Vt_h @8192 [64 d][64 n],
  // Vt_l @12288, P per wave @16384 + w*2048 ([32 q][64 k]). Total 48KB.
  __shared__ u16 lds[24576];
  const int t = threadIdx.x, w = t >> 6, lane = t & 63, g = lane >> 4, cl = lane & 15;
  int bid = (blockIdx.x & 7) * 64 + (blockIdx.x >> 3);  // same-bh blocks -> same XCD
  const int bh = bid >> 4, qt = bid & 15;
  const int n0 = qt * 128;
  const int PH = 16384 + w * 2048;

  // Q fragments (B operand; pre-scaled by SCALE)
  bf16x8 qfh[2][2], qfl[2][2];
#pragma unroll
  for (int fm = 0; fm < 2; ++fm) {
    int rg = bh * 2048 + n0 + w * 32 + fm * 16 + cl;
#pragma unroll
    for (int ks = 0; ks < 2; ++ks) {
      qfh[fm][ks] = *(const bf16x8*)&Qh[rg * 64 + ks * 32 + g * 8];
      qfl[fm][ks] = *(const bf16x8*)&Ql[rg * 64 + ks * 32 + g * 8];
    }
  }

  f32x4 o[2][4] = {};
  float mrun[2] = {-1e30f, -1e30f}, lrun[2] = {0.f, 0.f};
  const int bsrc = (lane & 48) | ((lane >> 2) & 12);  // lane with cl = 4g (same g)

  for (int kt = 0; kt < 32; ++kt) {
#pragma unroll
    for (int j = 0; j < 8; ++j) {
      int gs = j * 256 + t;
      int tensor = gs >> 9, s = gs & 511, row = s >> 3;
      int c = (s & 7) ^ (row & 7);
      const u16* src;
      if (tensor == 0)      src = Kh + (bh * 2048 + kt * 64 + row) * 64 + c * 8;
      else if (tensor == 1) src = Kl + (bh * 2048 + kt * 64 + row) * 64 + c * 8;
      else if (tensor == 2) src = Vh + (bh * 64 + row) * 2048 + kt * 64 + c * 8;
      else                  src = Vl + (bh * 64 + row) * 2048 + kt * 64 + c * 8;
      async16(&lds[(unsigned)(gs & ~63) * 8], src);
    }
    __syncthreads();

    // S^T = K.Q (3-term split): st[fm][fn][r] = S[q=..+cl][k=fn*16+4g+r]
    f32x4 st[2][4] = {};
    __builtin_amdgcn_s_setprio(1);
#pragma unroll
    for (int fn = 0; fn < 4; ++fn) {
      int krow = fn * 16 + cl;
#pragma unroll
      for (int ks = 0; ks < 2; ++ks) {
        int idx = krow * 64 + (((4 * ks + g) ^ (krow & 7)) * 8);
        bf16x8 kfh = *(const bf16x8*)&lds[idx];
        bf16x8 kfl = *(const bf16x8*)&lds[4096 + idx];
#pragma unroll
        for (int fm = 0; fm < 2; ++fm) {
          st[fm][fn] = MFMA(kfh, qfh[fm][ks], st[fm][fn]);
          st[fm][fn] = MFMA(kfl, qfh[fm][ks], st[fm][fn]);
          st[fm][fn] = MFMA(kfh, qfl[fm][ks], st[fm][fn]);
        }
      }
    }
    __builtin_amdgcn_s_setprio(0);

    // online softmax, lane-owns-row
#pragma unroll
    for (int fm = 0; fm < 2; ++fm) {
      float pmax = st[fm][0][0];
#pragma unroll
      for (int fn = 0; fn < 4; ++fn)
#pragma unroll
        for (int r = 0; r < 4; ++r) pmax = fmaxf(pmax, st[fm][fn][r]);
      pmax = fmaxf(pmax, __shfl_xor(pmax, 16));
      pmax = fmaxf(pmax, __shfl_xor(pmax, 32));
      float mnew = fmaxf(mrun[fm], pmax);
      float esc = __expf(mrun[fm] - mnew);
      mrun[fm] = mnew;
      float psum = 0.f;
      unsigned upk[4][2];
#pragma unroll
      for (int fn = 0; fn < 4; ++fn) {
        float p0 = __expf(st[fm][fn][0] - mnew);
        float p1 = __expf(st[fm][fn][1] - mnew);
        float p2 = __expf(st[fm][fn][2] - mnew);
        float p3 = __expf(st[fm][fn][3] - mnew);
        psum += (p0 + p1) + (p2 + p3);
        upk[fn][0] = (unsigned)f2bf(p0) | ((unsigned)f2bf(p1) << 16);
        upk[fn][1] = (unsigned)f2bf(p2) | ((unsigned)f2bf(p3) << 16);
      }
      psum += __shfl_xor(psum, 16);
      psum += __shfl_xor(psum, 32);
      lrun[fm] = lrun[fm] * esc + psum;
      // broadcast esc from row-owner lanes (cl = 4g+r) and rescale O
      float e0 = __shfl(esc, bsrc), e1 = __shfl(esc, bsrc | 1);
      float e2 = __shfl(esc, bsrc | 2), e3 = __shfl(esc, bsrc | 3);
#pragma unroll
      for (int fd = 0; fd < 4; ++fd) {
        o[fm][fd][0] *= e0; o[fm][fd][1] *= e1;
        o[fm][fd][2] *= e2; o[fm][fd][3] *= e3;
      }
      // write P rows (rq = fm*16+cl, keys fn*16+4g+0..3), XOR-swizzled
      int rq = fm * 16 + cl;
      int swz = (rq & 7) << 3;
#pragma unroll
      for (int fn = 0; fn < 4; ++fn) {
        int addr = (rq * 64 + fn * 16 + 4 * g) ^ swz;
        *(uint2*)&lds[PH + addr] = make_uint2(upk[fn][0], upk[fn][1]);
      }
    }

    // P A-fragments back from private LDS (same-wave, no barrier needed)
    bf16x8 pa[2][2];
#pragma unroll
    for (int fm = 0; fm < 2; ++fm) {
      int rq = fm * 16 + cl;
      int swz = (rq & 7) << 3;
#pragma unroll
      for (int ks = 0; ks < 2; ++ks) {
        int addr = (rq * 64 + ks * 32 + 8 * g) ^ swz;
        pa[fm][ks] = *(const bf16x8*)&lds[PH + addr];
      }
    }

    // O += P.V (2-term: ph*vh + ph*vl)
    __builtin_amdgcn_s_setprio(1);
#pragma unroll
    for (int fd = 0; fd < 4; ++fd) {
      int vrow = fd * 16 + cl;
#pragma unroll
      for (int ks = 0; ks < 2; ++ks) {
        int idx = vrow * 64 + (((4 * ks + g) ^ (vrow & 7)) * 8);
        bf16x8 vfh = *(const bf16x8*)&lds[8192 + idx];
        bf16x8 vfl = *(const bf16x8*)&lds[12288 + idx];
#pragma unroll
        for (int fm = 0; fm < 2; ++fm) {
          o[fm][fd] = MFMA(pa[fm][ks], vfh, o[fm][fd]);
          o[fm][fd] = MFMA(pa[fm][ks], vfl, o[fm][fd]);
        }
      }
    }
    __builtin_amdgcn_s_setprio(0);
    __syncthreads();
  }

  // normalize + write O (split, [token][h*64+d] layout for proj GEMM)
  const int b = bh >> 4, h = bh & 15;
#pragma unroll
  for (int fm = 0; fm < 2; ++fm) {
    float l0 = __shfl(lrun[fm], bsrc), l1 = __shfl(lrun[fm], bsrc | 1);
    float l2 = __shfl(lrun[fm], bsrc | 2), l3 = __shfl(lrun[fm], bsrc | 3);
    float inv[4] = {1.0f / l0, 1.0f / l1, 1.0f / l2, 1.0f / l3};
#pragma unroll
    for (int fd = 0; fd < 4; ++fd)
#pragma unroll
      for (int r = 0; r < 4; ++r) {
        float v = o[fm][fd][r] * inv[r];
        u16 hh = f2bf(v), ll = f2bf(v - bf2f(hh));
        int rowg = b * 2048 + n0 + w * 32 + fm * 16 + 4 * g + r;
        int colg = h * 64 + fd * 16 + cl;
        Oh[rowg * 1024 + colg] = hh;
        Ol[rowg * 1024 + colg] = ll;
      }
  }
}

extern "C" void kernel_launch(void* const* d_in, const int* in_sizes, int n_in,
                              void* d_out, int out_size, void* d_ws, size_t ws_size,
                              hipStream_t stream) {
  const float* x  = (const float*)d_in[0];
  const float* Wq = (const float*)d_in[1];
  const float* bq = (const float*)d_in[2];
  const float* Wp = (const float*)d_in[3];
  const float* bp = (const float*)d_in[4];
  float* out = (float*)d_out;
  char* ws = (char*)d_ws;

  u16* Xh  = (u16*)(ws + 0);         // also Oh
  u16* Xl  = (u16*)(ws + 8388608);   // also Ol
  u16* Wqh = (u16*)(ws + 16777216);
  u16* Wql = (u16*)(ws + 23068672);
  u16* Wph = (u16*)(ws + 29360128);
  u16* Wpl = (u16*)(ws + 31457280);
  u16* Qh  = (u16*)(ws + 33554432);
  u16* Ql  = (u16*)(ws + 41943040);
  u16* Kh  = (u16*)(ws + 50331648);
  u16* Kl  = (u16*)(ws + 58720256);
  u16* Vh  = (u16*)(ws + 67108864);
  u16* Vl  = (u16*)(ws + 75497472);  // end 83886080 (80MB)

  k_split_all<<<8192, 256, 0, stream>>>(x, Wq, Wp, Xh, Xl, Wqh, Wql, Wph, Wpl);

  k_gemm<0><<<32 * 24, 256, 0, stream>>>(Xh, Xl, Wqh, Wql, bq,
                                         Qh, Ql, Kh, Kl, Vh, Vl, nullptr, 24);
  k_attn<<<512, 256, 0, stream>>>(Qh, Ql, Kh, Kl, Vh, Vl, Xh, Xl);
  k_gemm<1><<<32 * 8, 256, 0, stream>>>(Xh, Xl, Wph, Wpl, bp,
                                        nullptr, nullptr, nullptr, nullptr,
                                        nullptr, nullptr, out, 8);
}